// Round 3
// baseline (24274.434 us; speedup 1.0000x reference)
//
#include <hip/hip_runtime.h>
#include <math.h>

#define B   64
#define TS  64
#define TT  64
#define E   512
#define H   512
#define DH  1024
#define VT  32000

typedef __attribute__((ext_vector_type(8))) short short8;
typedef __attribute__((ext_vector_type(4))) float floatx4;

__device__ __forceinline__ ushort f2bf(float f) {
    union { float f; unsigned int i; } v; v.f = f;
    unsigned int u = v.i;
    return (ushort)((u + 0x7fffu + ((u >> 16) & 1u)) >> 16);
}
// load 8 contiguous f32, round-to-nearest-even to bf16, pack into MFMA fragment
__device__ __forceinline__ short8 ld8bf(const float* p) {
    short8 r;
#pragma unroll
    for (int i = 0; i < 8; i++) r[i] = (short)f2bf(p[i]);
    return r;
}
__device__ __forceinline__ float sigm(float x) { return 1.0f / (1.0f + expf(-x)); }

// ---------------------------------------------------------------------------
// GEMM: C[M=64,N] = A[M,K](f32) * W[N,K](f32)^T + bias[N], bf16 MFMA fragments.
// Block = 256 = 4 waves (2x2), block tile 64x64, wave tile 32x32 (2x2 MFMA).
// Grid: (N/64, 1). outf: raw f32; outt: tanh f32 (either may be null).
// MFMA layouts (HW-verified m89): A/B frag row=lane&15, k=(lane>>4)*8+j;
// C/D row=(lane>>4)*4+r, col=lane&15.
// ---------------------------------------------------------------------------
__global__ __launch_bounds__(256) void gemm_bt(
    const float* __restrict__ A, const float* __restrict__ W,
    const float* __restrict__ bias,
    float* __restrict__ outf, int ldof,
    float* __restrict__ outt, int ldot, int K)
{
    const int tid  = threadIdx.x;
    const int wave = tid >> 6;
    const int lane = tid & 63;
    const int wm = wave >> 1, wn = wave & 1;
    const int l15 = lane & 15, quad = lane >> 4;
    const int m0 = wm * 32;
    const int n0 = blockIdx.x * 64 + wn * 32;
    const int koff = quad * 8;

    floatx4 acc[2][2] = {};
    const float* Ap0 = A + (size_t)(m0 + l15) * K + koff;
    const float* Ap1 = A + (size_t)(m0 + 16 + l15) * K + koff;
    const float* Wp0 = W + (size_t)(n0 + l15) * K + koff;
    const float* Wp1 = W + (size_t)(n0 + 16 + l15) * K + koff;
    for (int kb = 0; kb < K; kb += 32) {
        short8 a0 = ld8bf(Ap0 + kb);
        short8 a1 = ld8bf(Ap1 + kb);
        short8 w0 = ld8bf(Wp0 + kb);
        short8 w1 = ld8bf(Wp1 + kb);
        acc[0][0] = __builtin_amdgcn_mfma_f32_16x16x32_bf16(a0, w0, acc[0][0], 0, 0, 0);
        acc[0][1] = __builtin_amdgcn_mfma_f32_16x16x32_bf16(a0, w1, acc[0][1], 0, 0, 0);
        acc[1][0] = __builtin_amdgcn_mfma_f32_16x16x32_bf16(a1, w0, acc[1][0], 0, 0, 0);
        acc[1][1] = __builtin_amdgcn_mfma_f32_16x16x32_bf16(a1, w1, acc[1][1], 0, 0, 0);
    }
    for (int i = 0; i < 2; i++)
        for (int j = 0; j < 2; j++) {
            int col = n0 + j * 16 + l15;
            float bv = bias ? bias[col] : 0.0f;
            for (int r = 0; r < 4; r++) {
                int row = m0 + i * 16 + quad * 4 + r;
                float v = acc[i][j][r] + bv;
                if (outf) outf[(size_t)row * ldof + col] = v;
                if (outt) outt[(size_t)row * ldot + col] = tanhf(v);
            }
        }
}

// ---------------------------------------------------------------------------
// Encoder step, both directions, x@Wih^T fused:
// gates = sv[:,t,:] @ Wih^T + h_prev @ Whh^T + b, then LSTM cell.
// Grid: 64 blocks (dir = bid>>5, jt = bid&31). Wave w = gate type w for
// h-cols [jt*16, jt*16+16) over all 64 batches (4 MFMA m-tiles).
// ---------------------------------------------------------------------------
__global__ __launch_bounds__(256) void enc_step(
    const float* __restrict__ Wih_f, const float* __restrict__ Whh_f,
    const float* __restrict__ bias_f,
    const float* __restrict__ Wih_r, const float* __restrict__ Whh_r,
    const float* __restrict__ bias_r,
    const float* __restrict__ sv,
    const float* __restrict__ hprev, float* __restrict__ hnext,   // [dir][B][H]
    const float* __restrict__ cprev, float* __restrict__ cnext,
    float* __restrict__ Henc, float* __restrict__ final_cat,
    const int* __restrict__ src_lens, int t)
{
    const int d  = blockIdx.x >> 5;
    const int jt = blockIdx.x & 31;
    const int tid = threadIdx.x;
    const int wave = tid >> 6, lane = tid & 63;
    const int l15 = lane & 15, quad = lane >> 4;
    const float* Wih  = d ? Wih_r : Wih_f;
    const float* Whh  = d ? Whh_r : Whh_f;
    const float* bias = d ? bias_r : bias_f;
    const float* hp = hprev + d * (B * H);
    const int n0 = wave * H + jt * 16;      // column in 4H gate space
    const int koff = quad * 8;

    floatx4 acc[4] = {};
    const float* Wp = Wih + (size_t)(n0 + l15) * E + koff;
    for (int kb = 0; kb < E; kb += 32) {
        short8 w = ld8bf(Wp + kb);
        for (int mi = 0; mi < 4; mi++) {
            short8 a = ld8bf(sv + ((size_t)(mi * 16 + l15) * TS + t) * E + kb + koff);
            acc[mi] = __builtin_amdgcn_mfma_f32_16x16x32_bf16(a, w, acc[mi], 0, 0, 0);
        }
    }
    const float* Wp2 = Whh + (size_t)(n0 + l15) * H + koff;
    for (int kb = 0; kb < H; kb += 32) {
        short8 w = ld8bf(Wp2 + kb);
        for (int mi = 0; mi < 4; mi++) {
            short8 a = ld8bf(hp + (size_t)(mi * 16 + l15) * H + kb + koff);
            acc[mi] = __builtin_amdgcn_mfma_f32_16x16x32_bf16(a, w, acc[mi], 0, 0, 0);
        }
    }

    __shared__ float gl[4][B][16];
    float bv = bias[n0 + l15];
    for (int mi = 0; mi < 4; mi++)
        for (int r = 0; r < 4; r++) {
            int b_ = mi * 16 + quad * 4 + r;
            gl[wave][b_][l15] = acc[mi][r] + bv;
        }
    __syncthreads();

    for (int p = tid; p < B * 16; p += 256) {
        int b_ = p >> 4, jl = p & 15;
        int j = jt * 16 + jl;
        float gi = gl[0][b_][jl], gf = gl[1][b_][jl];
        float gg = gl[2][b_][jl], go = gl[3][b_][jl];
        float cp = cprev[(d * B + b_) * H + j];
        float cn = sigm(gf) * cp + sigm(gi) * tanhf(gg);
        float hn = sigm(go) * tanhf(cn);
        cnext[(d * B + b_) * H + j] = cn;
        hnext[(d * B + b_) * H + j] = hn;
        Henc[(size_t)(b_ * TS + t) * DH + d * H + j] = hn;
        if (t == src_lens[b_] - 1) {
            final_cat[b_ * (4 * H) + d * H + j] = hn;           // H part
            final_cat[b_ * (4 * H) + 2 * H + d * H + j] = cn;   // C part
        }
    }
}

// ---------------------------------------------------------------------------
// Decoder gates GEMM, inputs fused: A row b = [emb(trg_tok[b,t]) | av[b] | h[b]]
// (K = 512+1024+1024), W = [dec_Wih | dec_Whh]. gates[b, 4096] f32.
// Grid (64): block tile 64x64 over N=4096, M=64.
// ---------------------------------------------------------------------------
__global__ __launch_bounds__(256) void dec_gates(
    const float* __restrict__ trg_emb, const int* __restrict__ trg_tokens,
    const float* __restrict__ av, const float* __restrict__ hc,
    const float* __restrict__ Wih, const float* __restrict__ Whh,
    const float* __restrict__ bias, float* __restrict__ gates, int t)
{
    const int tid = threadIdx.x;
    const int wave = tid >> 6, lane = tid & 63;
    const int wm = wave >> 1, wn = wave & 1;
    const int l15 = lane & 15, quad = lane >> 4;
    const int m0 = wm * 32;
    const int n0 = blockIdx.x * 64 + wn * 32;
    const int koff = quad * 8;
    const int b0 = m0 + l15, b1 = m0 + 16 + l15;

    const float* e0 = trg_emb + (size_t)trg_tokens[b0 * TT + t] * E + koff;
    const float* e1 = trg_emb + (size_t)trg_tokens[b1 * TT + t] * E + koff;
    const float* w0p = Wih + (size_t)(n0 + l15) * 1536 + koff;
    const float* w1p = Wih + (size_t)(n0 + 16 + l15) * 1536 + koff;

    floatx4 acc[2][2] = {};
    // segment 1: embedding, k in [0, 512)
    for (int kb = 0; kb < E; kb += 32) {
        short8 a0 = ld8bf(e0 + kb);
        short8 a1 = ld8bf(e1 + kb);
        short8 w0 = ld8bf(w0p + kb);
        short8 w1 = ld8bf(w1p + kb);
        acc[0][0] = __builtin_amdgcn_mfma_f32_16x16x32_bf16(a0, w0, acc[0][0], 0, 0, 0);
        acc[0][1] = __builtin_amdgcn_mfma_f32_16x16x32_bf16(a0, w1, acc[0][1], 0, 0, 0);
        acc[1][0] = __builtin_amdgcn_mfma_f32_16x16x32_bf16(a1, w0, acc[1][0], 0, 0, 0);
        acc[1][1] = __builtin_amdgcn_mfma_f32_16x16x32_bf16(a1, w1, acc[1][1], 0, 0, 0);
    }
    // segment 2: av, k in [512, 1536) -> Wih cols 512+
    const float* a0p = av + (size_t)b0 * DH + koff;
    const float* a1p = av + (size_t)b1 * DH + koff;
    for (int kb = 0; kb < DH; kb += 32) {
        short8 a0 = ld8bf(a0p + kb);
        short8 a1 = ld8bf(a1p + kb);
        short8 w0 = ld8bf(w0p + E + kb);
        short8 w1 = ld8bf(w1p + E + kb);
        acc[0][0] = __builtin_amdgcn_mfma_f32_16x16x32_bf16(a0, w0, acc[0][0], 0, 0, 0);
        acc[0][1] = __builtin_amdgcn_mfma_f32_16x16x32_bf16(a0, w1, acc[0][1], 0, 0, 0);
        acc[1][0] = __builtin_amdgcn_mfma_f32_16x16x32_bf16(a1, w0, acc[1][0], 0, 0, 0);
        acc[1][1] = __builtin_amdgcn_mfma_f32_16x16x32_bf16(a1, w1, acc[1][1], 0, 0, 0);
    }
    // segment 3: h (hc[:, :DH]) with Whh
    const float* h0p = hc + (size_t)b0 * (2 * DH) + koff;
    const float* h1p = hc + (size_t)b1 * (2 * DH) + koff;
    const float* v0p = Whh + (size_t)(n0 + l15) * DH + koff;
    const float* v1p = Whh + (size_t)(n0 + 16 + l15) * DH + koff;
    for (int kb = 0; kb < DH; kb += 32) {
        short8 a0 = ld8bf(h0p + kb);
        short8 a1 = ld8bf(h1p + kb);
        short8 w0 = ld8bf(v0p + kb);
        short8 w1 = ld8bf(v1p + kb);
        acc[0][0] = __builtin_amdgcn_mfma_f32_16x16x32_bf16(a0, w0, acc[0][0], 0, 0, 0);
        acc[0][1] = __builtin_amdgcn_mfma_f32_16x16x32_bf16(a0, w1, acc[0][1], 0, 0, 0);
        acc[1][0] = __builtin_amdgcn_mfma_f32_16x16x32_bf16(a1, w0, acc[1][0], 0, 0, 0);
        acc[1][1] = __builtin_amdgcn_mfma_f32_16x16x32_bf16(a1, w1, acc[1][1], 0, 0, 0);
    }

    for (int i = 0; i < 2; i++)
        for (int j = 0; j < 2; j++) {
            int col = n0 + j * 16 + l15;
            float bv = bias[col];
            for (int r = 0; r < 4; r++) {
                int row = m0 + i * 16 + quad * 4 + r;
                gates[(size_t)row * (4 * DH) + col] = acc[i][j][r] + bv;
            }
        }
}

// ---------------------------------------------------------------------------
__global__ void embed_src(const int* __restrict__ toks, const float* __restrict__ emb,
                          float* __restrict__ out)
{
    int r = blockIdx.x;                  // r = b*TS + t
    int tok = toks[r];
    for (int e = threadIdx.x; e < E; e += 256)
        out[(size_t)r * E + e] = emb[(size_t)tok * E + e];
}

__global__ void dec_cell(const float* __restrict__ gates, float* __restrict__ c,
                         float* __restrict__ hc)
{
    int idx = blockIdx.x * 256 + threadIdx.x;   // B*DH
    int b_ = idx >> 10, j = idx & 1023;
    const float* g = gates + (size_t)b_ * 4 * DH;
    float cn = sigm(g[DH + j]) * c[idx] + sigm(g[j]) * tanhf(g[2 * DH + j]);
    c[idx] = cn;
    hc[(size_t)b_ * 2 * DH + j] = sigm(g[3 * DH + j]) * tanhf(cn);
}

// One block per batch row: scores -> masked softmax -> ctx into hc[:, DH:]
__global__ __launch_bounds__(256) void attn_kernel(
    const float* __restrict__ Henc, float* __restrict__ hc,
    const int* __restrict__ src_lens)
{
    int b_ = blockIdx.x;
    int tid = threadIdx.x;
    __shared__ float red[256];
    __shared__ float attn[TS];
    const float* h = hc + (size_t)b_ * 2 * DH;
    int t = tid & 63, part = tid >> 6;
    const float* He = Henc + (size_t)(b_ * TS + t) * DH;
    float pp = 0.f;
    for (int j = part * 256; j < part * 256 + 256; j++)
        pp += h[j] * He[j];
    red[tid] = pp;
    __syncthreads();
    if (tid < 64) {
        float s = red[tid] + red[tid + 64] + red[tid + 128] + red[tid + 192];
        if (tid >= src_lens[b_]) s = -1e9f;
        float m = s;
        for (int off = 32; off >= 1; off >>= 1) m = fmaxf(m, __shfl_xor(m, off));
        float e = expf(s - m);
        float sum = e;
        for (int off = 32; off >= 1; off >>= 1) sum += __shfl_xor(sum, off);
        attn[tid] = e / sum;
    }
    __syncthreads();
    for (int k = 0; k < 4; k++) {
        int j = k * 256 + tid;
        float a = 0.f;
        for (int t2 = 0; t2 < TS; t2++)
            a += attn[t2] * Henc[(size_t)(b_ * TS + t2) * DH + j];
        hc[(size_t)b_ * 2 * DH + DH + j] = a;
    }
}

// One block per batch row: logsumexp over VT, write per-(t,b) masked lsm term
__global__ __launch_bounds__(256) void loss_kernel(
    const float* __restrict__ logits, const int* __restrict__ trg_tokens,
    const int* __restrict__ trg_lens, float* __restrict__ nll_buf, int t)
{
    int b_ = blockIdx.x, tid = threadIdx.x;
    const float* row = logits + (size_t)b_ * VT;
    __shared__ float red[256];
    float m = -1e30f;
    for (int i = tid; i < VT; i += 256) m = fmaxf(m, row[i]);
    red[tid] = m; __syncthreads();
    for (int s = 128; s >= 1; s >>= 1) {
        if (tid < s) red[tid] = fmaxf(red[tid], red[tid + s]);
        __syncthreads();
    }
    m = red[0]; __syncthreads();
    float sum = 0.f;
    for (int i = tid; i < VT; i += 256) sum += expf(row[i] - m);
    red[tid] = sum; __syncthreads();
    for (int s = 128; s >= 1; s >>= 1) {
        if (tid < s) red[tid] += red[tid + s];
        __syncthreads();
    }
    if (tid == 0) {
        float lse = m + logf(red[0]);
        int gold = trg_tokens[b_ * TT + t + 1];
        nll_buf[t * B + b_] = (t + 1 < trg_lens[b_]) ? (row[gold] - lse) : 0.f;
    }
}

__global__ void init_zero(float* h0, float* c0, float* av)
{
    int idx = blockIdx.x * 256 + threadIdx.x;   // 65536
    h0[idx] = 0.f;
    c0[idx] = 0.f;
    av[idx] = 0.f;
}

__global__ __launch_bounds__(256) void write_out(const float* __restrict__ nll_buf,
                                                 float* __restrict__ out)
{
    __shared__ float red[256];
    float s = 0.f;
    for (int i = threadIdx.x; i < (TT - 1) * B; i += 256) s += nll_buf[i];
    red[threadIdx.x] = s; __syncthreads();
    for (int st = 128; st >= 1; st >>= 1) {
        if (threadIdx.x < st) red[threadIdx.x] += red[threadIdx.x + st];
        __syncthreads();
    }
    if (threadIdx.x == 0) out[0] = red[0];
}

// ---------------------------------------------------------------------------
extern "C" void kernel_launch(void* const* d_in, const int* in_sizes, int n_in,
                              void* d_out, int out_size, void* d_ws, size_t ws_size,
                              hipStream_t stream)
{
    const int*   src_tokens = (const int*)d_in[0];
    const int*   src_lens   = (const int*)d_in[1];
    const int*   trg_tokens = (const int*)d_in[2];
    const int*   trg_lens   = (const int*)d_in[3];
    const float* src_emb    = (const float*)d_in[4];
    const float* trg_emb    = (const float*)d_in[5];
    const float* enc_Wih    = (const float*)d_in[6];
    const float* enc_Whh    = (const float*)d_in[7];
    const float* enc_b      = (const float*)d_in[8];
    const float* rev_Wih    = (const float*)d_in[9];
    const float* rev_Whh    = (const float*)d_in[10];
    const float* rev_b      = (const float*)d_in[11];
    const float* dec_Wih    = (const float*)d_in[12];
    const float* dec_Whh    = (const float*)d_in[13];
    const float* dec_b      = (const float*)d_in[14];
    const float* hid_W      = (const float*)d_in[15];
    const float* hid_b      = (const float*)d_in[16];
    const float* out_W      = (const float*)d_in[17];
    const float* out_b      = (const float*)d_in[18];
    const float* init_W     = (const float*)d_in[19];
    const float* init_b     = (const float*)d_in[20];

    char* ws = (char*)d_ws;
    size_t off = 0;
    auto alloc = [&](size_t bytes) -> void* {
        void* p = ws + off;
        off = (off + bytes + 255) & ~(size_t)255;
        return p;
    };
    // total ~39 MB
    float* sv        = (float*)alloc((size_t)B * TS * E * 4);        // 8.4 MB
    float* Henc      = (float*)alloc((size_t)B * TS * DH * 4);       // 16.8 MB
    float* hbuf      = (float*)alloc((size_t)2 * 2 * B * H * 4);     // [par][dir][B][H]
    float* cbuf      = (float*)alloc((size_t)2 * 2 * B * H * 4);
    float* final_cat = (float*)alloc((size_t)B * 4 * H * 4);
    float* gates     = (float*)alloc((size_t)B * 4 * DH * 4);
    float* dec_c     = (float*)alloc((size_t)B * DH * 4);
    float* hc        = (float*)alloc((size_t)B * 2 * DH * 4);        // [h | ctx]
    float* av        = (float*)alloc((size_t)B * DH * 4);
    float* logits    = (float*)alloc((size_t)B * VT * 4);            // 8.2 MB
    float* nll_buf   = (float*)alloc((size_t)(TT - 1) * B * 4);

    // zero initial encoder state (parity 0), av0
    init_zero<<<256, 256, 0, stream>>>(hbuf, cbuf, av);

    // embeddings
    embed_src<<<B * TS, 256, 0, stream>>>(src_tokens, src_emb, sv);

    // encoder recurrence (both directions per launch; x@Wih fused in)
    for (int t = 0; t < TS; t++) {
        int par = t & 1;
        enc_step<<<64, 256, 0, stream>>>(
            enc_Wih, enc_Whh, enc_b, rev_Wih, rev_Whh, rev_b, sv,
            hbuf + (size_t)par * 2 * B * H, hbuf + (size_t)(par ^ 1) * 2 * B * H,
            cbuf + (size_t)par * 2 * B * H, cbuf + (size_t)(par ^ 1) * 2 * B * H,
            Henc, final_cat, src_lens, t);
    }

    // c0 = final_cat @ init_W^T + init_b (f32 -> dec_c); h0 = tanh(c0) -> hc[:, :DH]
    gemm_bt<<<dim3(DH / 64), 256, 0, stream>>>(final_cat, init_W, init_b,
                                               dec_c, DH, hc, 2 * DH, 2 * DH);

    // decoder
    for (int t = 0; t < TT - 1; t++) {
        dec_gates<<<dim3(4 * DH / 64), 256, 0, stream>>>(
            trg_emb, trg_tokens, av, hc, dec_Wih, dec_Whh, dec_b, gates, t);
        dec_cell<<<B * DH / 256, 256, 0, stream>>>(gates, dec_c, hc);
        attn_kernel<<<B, 256, 0, stream>>>(Henc, hc, src_lens);
        gemm_bt<<<dim3(DH / 64), 256, 0, stream>>>(hc, hid_W, hid_b,
                                                   av, DH, nullptr, 0, 2 * DH);
        gemm_bt<<<dim3(VT / 64), 256, 0, stream>>>(av, out_W, out_b,
                                                   logits, VT, nullptr, 0, DH);
        loss_kernel<<<B, 256, 0, stream>>>(logits, trg_tokens, trg_lens, nll_buf, t);
    }

    write_out<<<1, 256, 0, stream>>>(nll_buf, (float*)d_out);
}